// Round 1
// baseline (3031.697 us; speedup 1.0000x reference)
//
#include <hip/hip_runtime.h>
#include <hip/hip_bf16.h>
#include <math.h>

typedef __hip_bfloat16 bf16;

#define NB 32
#define NC 32
#define NNODE 300
#define NT 64
#define NDIM 40
#define KTOP 20
#define NSKIP 64
#define NTOUT 58
#define SLAB 17400        // NNODE*NTOUT
#define BSLAB 556800      // NC*SLAB
#define XEL 17817600      // NB*BSLAB

__device__ __forceinline__ float b2f(bf16 v){ return __bfloat162float(v); }
__device__ __forceinline__ bf16 f2b(float v){ return __float2bfloat16(v); }

// ---------------- graph construction ----------------
__global__ void k_nodes(const float* __restrict__ emb1, const float* __restrict__ emb2,
                        const float* __restrict__ l1w, const float* __restrict__ l1b,
                        const float* __restrict__ l2w, const float* __restrict__ l2b,
                        const int* __restrict__ idxp,
                        float* __restrict__ n1, float* __restrict__ n2){
  int i = blockIdx.x; int d = threadIdx.x;
  if (d >= NDIM) return;
  int r = idxp[i];
  float a1 = l1b[d], a2 = l2b[d];
  for (int k=0;k<NDIM;++k){
    a1 = fmaf(emb1[r*NDIM+k], l1w[d*NDIM+k], a1);
    a2 = fmaf(emb2[r*NDIM+k], l2w[d*NDIM+k], a2);
  }
  n1[i*NDIM+d] = tanhf(3.0f*a1);
  n2[i*NDIM+d] = tanhf(3.0f*a2);
}

// one block (1 wave) per row: A row, relu(tanh), iterative top-20, masked write
__global__ void __launch_bounds__(64) k_adjrow(const float* __restrict__ n1,
                                               const float* __restrict__ n2,
                                               float* __restrict__ Am){
  int i = blockIdx.x; int lane = threadIdx.x;
  __shared__ float rowo[NNODE];
  __shared__ float rowv[NNODE];
  __shared__ int   sel[NNODE];
  for (int j=lane;j<NNODE;j+=64){
    float a = 0.f;
    #pragma unroll
    for (int k=0;k<NDIM;++k){
      float a1 = n1[i*NDIM+k], a2 = n2[i*NDIM+k];      // uniform -> scalar
      a = fmaf(a1, n2[j*NDIM+k], a);
      a = fmaf(-a2, n1[j*NDIM+k], a);
    }
    float v = tanhf(3.0f*a);
    v = v > 0.f ? v : 0.f;
    rowo[j]=v; rowv[j]=v; sel[j]=0;
  }
  __syncthreads();
  for (int it=0; it<KTOP; ++it){
    float best = -1.f; int bi = 0x7fffffff;
    for (int j=lane;j<NNODE;j+=64){
      float v = rowv[j];
      if (v > best){ best=v; bi=j; }
    }
    #pragma unroll
    for (int off=32; off; off>>=1){
      float ov = __shfl_xor(best, off);
      int   oi = __shfl_xor(bi, off);
      if (ov > best || (ov == best && oi < bi)){ best=ov; bi=oi; }
    }
    if (lane==0){ sel[bi]=1; rowv[bi]=-2.f; }
    __syncthreads();
  }
  for (int j=lane;j<NNODE;j+=64)
    Am[i*NNODE+j] = sel[j] ? rowo[j] : 0.f;
}

// sparse row lists for Ah1 (r<300, rows of A) and Ah2 (r>=300, cols of A); slot0 = diag
__global__ void __launch_bounds__(64) k_csr(const float* __restrict__ Am,
                                            int* __restrict__ aidx, float* __restrict__ aval,
                                            int* __restrict__ acnt){
  int r = blockIdx.x; int lane = threadIdx.x;
  int v = (r < NNODE) ? r : r - NNODE;
  int*   ip = aidx + r*304;
  float* vp = aval + r*304;
  if (lane==0){ ip[0]=v; vp[0]=1.0f; }
  int cnt = 1; float s = 1.0f;
  for (int base=0; base<NNODE; base+=64){
    int j = base + lane; float val = 0.f; bool p = false;
    if (j < NNODE){
      val = (r < NNODE) ? Am[v*NNODE + j] : Am[j*NNODE + v];
      p = val > 0.f;
    }
    unsigned long long m = __ballot(p);
    int pre = __popcll(m & ((1ull << lane) - 1ull));
    if (p){ ip[cnt+pre]=j; vp[cnt+pre]=val; }
    cnt += __popcll(m);
    float vs = p ? val : 0.f;
    #pragma unroll
    for (int off=32; off; off>>=1) vs += __shfl_xor(vs, off);
    s += vs;
  }
  for (int e=lane; e<cnt; e+=64) vp[e] = vp[e] / s;
  if (lane==0) acnt[r]=cnt;
}

// ---------------- dilated inception (tanh * sigmoid), writes X bf16 ----------------
__global__ void __launch_bounds__(64) k_incep(const float* __restrict__ x,
    const float* __restrict__ fw2,const float* __restrict__ fb2,const float* __restrict__ gw2,const float* __restrict__ gb2,
    const float* __restrict__ fw3,const float* __restrict__ fb3,const float* __restrict__ gw3,const float* __restrict__ gb3,
    const float* __restrict__ fw6,const float* __restrict__ fb6,const float* __restrict__ gw6,const float* __restrict__ gb6,
    const float* __restrict__ fw7,const float* __restrict__ fb7,const float* __restrict__ gw7,const float* __restrict__ gb7,
    bf16* __restrict__ X){
  int b = blockIdx.x / NNODE, n = blockIdx.x % NNODE;
  int lane = threadIdx.x;
  __shared__ float xs[NC*NT];
  const float* xb = x + ((size_t)(b*NC)*NNODE + n)*NT;
  for (int c=0;c<NC;++c) xs[c*NT+lane] = xb[(size_t)c*NNODE*NT + lane];
  __syncthreads();
  int t = lane; bool act = t < NTOUT; int tc = act ? t : 0;
  float af[32], ag[32];
  #pragma unroll
  for (int o=0;o<8;++o){
    af[o]=fb2[o]; af[8+o]=fb3[o]; af[16+o]=fb6[o]; af[24+o]=fb7[o];
    ag[o]=gb2[o]; ag[8+o]=gb3[o]; ag[16+o]=gb6[o]; ag[24+o]=gb7[o];
  }
  for (int ic=0; ic<NC; ++ic){
    float xv[7];
    #pragma unroll
    for (int d=0;d<7;++d) xv[d] = xs[ic*NT + tc + d];
    #pragma unroll
    for (int o=0;o<8;++o){
      #pragma unroll
      for (int tp=0;tp<2;++tp){ af[o]    = fmaf(fw2[(o*NC+ic)*2+tp], xv[5+tp], af[o]);    ag[o]    = fmaf(gw2[(o*NC+ic)*2+tp], xv[5+tp], ag[o]); }
      #pragma unroll
      for (int tp=0;tp<3;++tp){ af[8+o]  = fmaf(fw3[(o*NC+ic)*3+tp], xv[4+tp], af[8+o]);  ag[8+o]  = fmaf(gw3[(o*NC+ic)*3+tp], xv[4+tp], ag[8+o]); }
      #pragma unroll
      for (int tp=0;tp<6;++tp){ af[16+o] = fmaf(fw6[(o*NC+ic)*6+tp], xv[1+tp], af[16+o]); ag[16+o] = fmaf(gw6[(o*NC+ic)*6+tp], xv[1+tp], ag[16+o]); }
      #pragma unroll
      for (int tp=0;tp<7;++tp){ af[24+o] = fmaf(fw7[(o*NC+ic)*7+tp], xv[tp],   af[24+o]); ag[24+o] = fmaf(gw7[(o*NC+ic)*7+tp], xv[tp],   ag[24+o]); }
    }
  }
  if (act){
    size_t ob = (size_t)b*BSLAB + (size_t)n*NTOUT + t;
    #pragma unroll
    for (int o=0;o<NC;++o){
      float fo = tanhf(af[o]);
      float go = 1.f/(1.f+expf(-ag[o]));
      X[ob + (size_t)o*SLAB] = f2b(fo*go);
    }
  }
}

// ---------------- skip path ----------------
__global__ void k_wT(const float* __restrict__ sw, float* __restrict__ wT){
  int id = blockIdx.x*blockDim.x + threadIdx.x;
  if (id >= 1856*64) return;
  int kk = id >> 6, sc = id & 63;
  wT[kk*64 + sc] = sw[sc*1856 + kk];
}

__global__ void __launch_bounds__(256) k_skip(const bf16* __restrict__ X, const float* __restrict__ wT,
      const float* __restrict__ skip_b, const float* __restrict__ x_skip, float* __restrict__ out){
  int lane = threadIdx.x & 63;
  int gn = blockIdx.x*4 + (threadIdx.x >> 6);
  int b = gn / NNODE, n = gn % NNODE;
  const bf16* xsl = X + (size_t)b*BSLAB + (size_t)n*NTOUT;
  float acc = 0.f;
  for (int c=0;c<NC;++c){
    const bf16* xc = xsl + (size_t)c*SLAB;
    int kk0 = c*NTOUT;
    for (int t=0;t<NTOUT;++t){
      float xv = b2f(xc[t]);
      acc = fmaf(xv, wT[(kk0+t)*64 + lane], acc);
    }
  }
  size_t so = (size_t)b*NSKIP*NNODE + (size_t)lane*NNODE + n;
  out[(size_t)XEL + so] = acc + skip_b[lane] + x_skip[so];
}

// ---------------- graph diffusion hop: Hout = 0.05*X + 0.95*(Ah (x) Hin) ----------------
__global__ void __launch_bounds__(256) k_prop(const bf16* __restrict__ Hin, const bf16* __restrict__ Xb,
    bf16* __restrict__ Hout,
    const int* __restrict__ aidx, const float* __restrict__ aval, const int* __restrict__ acnt,
    int rowoff){
  int o = blockIdx.x*256 + threadIdx.x;
  int t = o % NTOUT; int v = (o / NTOUT) % NNODE; int bc = o / SLAB;
  int r = rowoff + v;
  int cnt = acnt[r];
  const int*   ip = aidx + r*304;
  const float* vp = aval + r*304;
  const bf16* hb = Hin + (size_t)bc*SLAB;
  float s = 0.f;
  for (int j=0;j<cnt;++j)
    s = fmaf(vp[j], b2f(hb[ip[j]*NTOUT + t]), s);
  float acc = 0.05f * b2f(Xb[o]) + 0.95f * s;
  Hout[o] = f2b(acc);
}

// ---------------- 1x1 conv accumulation passes ----------------
__global__ void k_wsum(const float* __restrict__ w1, const float* __restrict__ w2, float* __restrict__ wsum){
  int id = blockIdx.x*blockDim.x + threadIdx.x;
  if (id >= 1024) return;
  int c = id >> 5, c2 = id & 31;
  wsum[id] = w1[c*96 + c2] + w2[c*96 + c2];
}

__global__ void __launch_bounds__(256) k_mix1(const bf16* __restrict__ X, const bf16* __restrict__ HA,
    const bf16* __restrict__ HB, const float* __restrict__ wsum, const float* __restrict__ w1,
    const float* __restrict__ b1, const float* __restrict__ b2, float* __restrict__ out){
  int o = blockIdx.x*256 + threadIdx.x;            // 0 .. 556800
  int t = o % NTOUT; int v = (o / NTOUT) % NNODE; int b = o / SLAB;
  size_t base = (size_t)b*BSLAB + (size_t)v*NTOUT + t;
  float acc[32];
  #pragma unroll
  for (int c=0;c<32;++c) acc[c] = b1[c] + b2[c];
  for (int c2=0;c2<32;++c2){
    float xv = b2f(X[base + (size_t)c2*SLAB]);
    #pragma unroll
    for (int c=0;c<32;++c) acc[c] = fmaf(wsum[c*32+c2], xv, acc[c]);
  }
  for (int c2=0;c2<32;++c2){
    float hv = b2f(HA[base + (size_t)c2*SLAB]);
    #pragma unroll
    for (int c=0;c<32;++c) acc[c] = fmaf(w1[c*96+32+c2], hv, acc[c]);
  }
  for (int c2=0;c2<32;++c2){
    float hv = b2f(HB[base + (size_t)c2*SLAB]);
    #pragma unroll
    for (int c=0;c<32;++c) acc[c] = fmaf(w1[c*96+64+c2], hv, acc[c]);
  }
  #pragma unroll
  for (int c=0;c<32;++c) out[base + (size_t)c*SLAB] = acc[c];
}

__global__ void __launch_bounds__(256) k_mix2(const bf16* __restrict__ HA, const bf16* __restrict__ HB,
    const float* __restrict__ w2, const float* __restrict__ x, float* __restrict__ out){
  int o = blockIdx.x*256 + threadIdx.x;
  int t = o % NTOUT; int v = (o / NTOUT) % NNODE; int b = o / SLAB;
  size_t base = (size_t)b*BSLAB + (size_t)v*NTOUT + t;
  float acc[32];
  #pragma unroll
  for (int c=0;c<32;++c) acc[c] = out[base + (size_t)c*SLAB];
  for (int c2=0;c2<32;++c2){
    float hv = b2f(HA[base + (size_t)c2*SLAB]);
    #pragma unroll
    for (int c=0;c<32;++c) acc[c] = fmaf(w2[c*96+32+c2], hv, acc[c]);
  }
  for (int c2=0;c2<32;++c2){
    float hv = b2f(HB[base + (size_t)c2*SLAB]);
    #pragma unroll
    for (int c=0;c<32;++c) acc[c] = fmaf(w2[c*96+64+c2], hv, acc[c]);
  }
  #pragma unroll
  for (int c=0;c<32;++c){
    float res = x[((size_t)(b*NC+c)*NNODE + v)*NT + 6 + t];
    out[base + (size_t)c*SLAB] = acc[c] + res;
  }
}

// ---------------- layernorm ----------------
__global__ void __launch_bounds__(256) k_lnstat(const float* __restrict__ out, double* __restrict__ part){
  int blk = blockIdx.x; int b = blk >> 3, seg = blk & 7;
  const float* p = out + (size_t)b*BSLAB;
  int start = seg*69600, end = start + 69600;
  double s = 0.0, s2 = 0.0;
  for (int i = start + threadIdx.x; i < end; i += 256){
    double v = (double)p[i]; s += v; s2 += v*v;
  }
  #pragma unroll
  for (int off=32; off; off>>=1){ s += __shfl_down(s, off); s2 += __shfl_down(s2, off); }
  __shared__ double ls[4], ls2[4];
  int lane = threadIdx.x & 63, w = threadIdx.x >> 6;
  if (lane==0){ ls[w]=s; ls2[w]=s2; }
  __syncthreads();
  if (threadIdx.x==0){
    double a=0.0, a2=0.0;
    for (int i=0;i<4;++i){ a+=ls[i]; a2+=ls2[i]; }
    part[blk*2]=a; part[blk*2+1]=a2;
  }
}

__global__ void k_lnfin(const double* __restrict__ part, float* __restrict__ stats){
  int b = threadIdx.x; if (b >= 32) return;
  double s=0.0, s2=0.0;
  for (int seg=0; seg<8; ++seg){ s += part[(b*8+seg)*2]; s2 += part[(b*8+seg)*2+1]; }
  double n = (double)BSLAB;
  double mean = s/n;
  double var = s2/n - mean*mean;
  stats[b*2]   = (float)mean;
  stats[b*2+1] = (float)(1.0/sqrt(var + 1e-5));
}

__global__ void __launch_bounds__(256) k_lnapply(float* __restrict__ out, const float* __restrict__ stats,
        const float* __restrict__ lnw, const float* __restrict__ lnb, const int* __restrict__ idxp){
  int o = blockIdx.x*256 + threadIdx.x;
  int t = o % NTOUT; int v = (o / NTOUT) % NNODE; int c = (o / SLAB) % NC; int b = o / BSLAB;
  float mean = stats[b*2], rstd = stats[b*2+1];
  int vn = idxp[v];
  float wv = lnw[((size_t)c*NNODE + vn)*NTOUT + t];
  float bv = lnb[((size_t)c*NNODE + vn)*NTOUT + t];
  float vx = out[o];
  out[o] = (vx - mean)*rstd*wv + bv;
}

extern "C" void kernel_launch(void* const* d_in, const int* in_sizes, int n_in,
                              void* d_out, int out_size, void* d_ws, size_t ws_size,
                              hipStream_t stream) {
  (void)in_sizes; (void)n_in; (void)out_size; (void)ws_size;
  const float* x     = (const float*)d_in[0];
  const float* xskip = (const float*)d_in[1];
  const int*   idxp  = (const int*)d_in[2];
  const float* emb1  = (const float*)d_in[3];
  const float* emb2  = (const float*)d_in[4];
  const float* l1w   = (const float*)d_in[5];
  const float* l1b   = (const float*)d_in[6];
  const float* l2w   = (const float*)d_in[7];
  const float* l2b   = (const float*)d_in[8];
  const float* skw   = (const float*)d_in[9];
  const float* skb   = (const float*)d_in[10];
  const float* m1w   = (const float*)d_in[11];
  const float* m1b   = (const float*)d_in[12];
  const float* m2w   = (const float*)d_in[13];
  const float* m2b   = (const float*)d_in[14];
  const float* lnw   = (const float*)d_in[15];
  const float* lnb   = (const float*)d_in[16];
  const float* fw2=(const float*)d_in[17]; const float* fb2=(const float*)d_in[18];
  const float* gw2=(const float*)d_in[19]; const float* gb2=(const float*)d_in[20];
  const float* fw3=(const float*)d_in[21]; const float* fb3=(const float*)d_in[22];
  const float* gw3=(const float*)d_in[23]; const float* gb3=(const float*)d_in[24];
  const float* fw6=(const float*)d_in[25]; const float* fb6=(const float*)d_in[26];
  const float* gw6=(const float*)d_in[27]; const float* gb6=(const float*)d_in[28];
  const float* fw7=(const float*)d_in[29]; const float* fb7=(const float*)d_in[30];
  const float* gw7=(const float*)d_in[31]; const float* gb7=(const float*)d_in[32];
  float* out = (float*)d_out;

  char* wsbase = (char*)d_ws;
  size_t cur = 0;
  auto alloc = [&](size_t bytes)->char*{
    char* p = wsbase + cur;
    cur = (cur + bytes + 255) & ~(size_t)255;
    return p;
  };
  bf16*  X    = (bf16*) alloc((size_t)XEL*2);
  bf16*  HA   = (bf16*) alloc((size_t)XEL*2);
  bf16*  HB   = (bf16*) alloc((size_t)XEL*2);
  float* n1   = (float*)alloc(12000*4);
  float* n2   = (float*)alloc(12000*4);
  float* Am   = (float*)alloc(90000*4);
  int*   aidx = (int*)  alloc(600*304*4);
  float* aval = (float*)alloc(600*304*4);
  int*   acnt = (int*)  alloc(600*4);
  float* wT   = (float*)alloc(1856*64*4);
  float* wsum = (float*)alloc(1024*4);
  double* part = (double*)alloc(256*2*8);
  float* stats = (float*)alloc(64*4);

  // graph construction (tiny)
  k_nodes <<<NNODE, 64, 0, stream>>>(emb1, emb2, l1w, l1b, l2w, l2b, idxp, n1, n2);
  k_adjrow<<<NNODE, 64, 0, stream>>>(n1, n2, Am);
  k_csr   <<<2*NNODE, 64, 0, stream>>>(Am, aidx, aval, acnt);

  // dilated inception -> X (bf16)
  k_incep<<<NB*NNODE, 64, 0, stream>>>(x,
      fw2,fb2,gw2,gb2, fw3,fb3,gw3,gb3, fw6,fb6,gw6,gb6, fw7,fb7,gw7,gb7, X);

  // skip path
  k_wT  <<<(1856*64)/256, 256, 0, stream>>>(skw, wT);
  k_wsum<<<4, 256, 0, stream>>>(m1w, m2w, wsum);
  k_skip<<<(NB*NNODE)/4, 256, 0, stream>>>(X, wT, skb, xskip, out);

  // mixprop over Ah1
  k_prop<<<XEL/256, 256, 0, stream>>>(X,  X, HA, aidx, aval, acnt, 0);
  k_prop<<<XEL/256, 256, 0, stream>>>(HA, X, HB, aidx, aval, acnt, 0);
  k_mix1<<<BSLAB/256, 256, 0, stream>>>(X, HA, HB, wsum, m1w, m1b, m2b, out);

  // mixprop over Ah2 (= A^T), reuse hop buffers
  k_prop<<<XEL/256, 256, 0, stream>>>(X,  X, HA, aidx, aval, acnt, NNODE);
  k_prop<<<XEL/256, 256, 0, stream>>>(HA, X, HB, aidx, aval, acnt, NNODE);
  k_mix2<<<BSLAB/256, 256, 0, stream>>>(HA, HB, m2w, x, out);

  // layernorm
  k_lnstat<<<256, 256, 0, stream>>>(out, part);
  k_lnfin<<<1, 32, 0, stream>>>(part, stats);
  k_lnapply<<<XEL/256, 256, 0, stream>>>(out, stats, lnw, lnb, idxp);
}

// Round 2
// 1137.635 us; speedup vs baseline: 2.6649x; 2.6649x over previous
//
#include <hip/hip_runtime.h>
#include <hip/hip_bf16.h>
#include <math.h>

typedef __hip_bfloat16 bf16;

#define NB 32
#define NC 32
#define NNODE 300
#define NT 64
#define NDIM 40
#define KTOP 20
#define NSKIP 64
#define NTOUT 58
#define SLAB 17400        // NNODE*NTOUT
#define BSLAB 556800      // NC*SLAB
#define XEL 17817600      // NB*BSLAB

__device__ __forceinline__ float b2f(bf16 v){ return __bfloat162float(v); }
__device__ __forceinline__ bf16 f2b(float v){ return __float2bfloat16(v); }
__device__ __forceinline__ float fsig(float x){ return 1.0f/(1.0f + __expf(-x)); }
__device__ __forceinline__ float ftanh(float x){ return 2.0f*fsig(2.0f*x) - 1.0f; }

// ---------------- graph construction ----------------
__global__ void k_nodes(const float* __restrict__ emb1, const float* __restrict__ emb2,
                        const float* __restrict__ l1w, const float* __restrict__ l1b,
                        const float* __restrict__ l2w, const float* __restrict__ l2b,
                        const int* __restrict__ idxp,
                        float* __restrict__ n1, float* __restrict__ n2){
  int i = blockIdx.x; int d = threadIdx.x;
  if (d >= NDIM) return;
  int r = idxp[i];
  float a1 = l1b[d], a2 = l2b[d];
  for (int k=0;k<NDIM;++k){
    a1 = fmaf(emb1[r*NDIM+k], l1w[d*NDIM+k], a1);
    a2 = fmaf(emb2[r*NDIM+k], l2w[d*NDIM+k], a2);
  }
  n1[i*NDIM+d] = tanhf(3.0f*a1);
  n2[i*NDIM+d] = tanhf(3.0f*a2);
}

// one block (1 wave) per row: A row, relu(tanh), iterative top-20, masked write
__global__ void __launch_bounds__(64) k_adjrow(const float* __restrict__ n1,
                                               const float* __restrict__ n2,
                                               float* __restrict__ Am){
  int i = blockIdx.x; int lane = threadIdx.x;
  __shared__ float rowo[NNODE];
  __shared__ float rowv[NNODE];
  __shared__ int   sel[NNODE];
  for (int j=lane;j<NNODE;j+=64){
    float a = 0.f;
    #pragma unroll
    for (int k=0;k<NDIM;++k){
      float a1 = n1[i*NDIM+k], a2 = n2[i*NDIM+k];      // uniform -> scalar
      a = fmaf(a1, n2[j*NDIM+k], a);
      a = fmaf(-a2, n1[j*NDIM+k], a);
    }
    float v = tanhf(3.0f*a);
    v = v > 0.f ? v : 0.f;
    rowo[j]=v; rowv[j]=v; sel[j]=0;
  }
  __syncthreads();
  for (int it=0; it<KTOP; ++it){
    float best = -1.f; int bi = 0x7fffffff;
    for (int j=lane;j<NNODE;j+=64){
      float v = rowv[j];
      if (v > best){ best=v; bi=j; }
    }
    #pragma unroll
    for (int off=32; off; off>>=1){
      float ov = __shfl_xor(best, off);
      int   oi = __shfl_xor(bi, off);
      if (ov > best || (ov == best && oi < bi)){ best=ov; bi=oi; }
    }
    if (lane==0){ sel[bi]=1; rowv[bi]=-2.f; }
    __syncthreads();
  }
  for (int j=lane;j<NNODE;j+=64)
    Am[i*NNODE+j] = sel[j] ? rowo[j] : 0.f;
}

// sparse row lists for Ah1 (r<300, rows of A) and Ah2 (r>=300, cols of A); slot0 = diag
__global__ void __launch_bounds__(64) k_csr(const float* __restrict__ Am,
                                            int* __restrict__ aidx, float* __restrict__ aval,
                                            int* __restrict__ acnt){
  int r = blockIdx.x; int lane = threadIdx.x;
  int v = (r < NNODE) ? r : r - NNODE;
  int*   ip = aidx + r*304;
  float* vp = aval + r*304;
  if (lane==0){ ip[0]=v; vp[0]=1.0f; }
  int cnt = 1; float s = 1.0f;
  for (int base=0; base<NNODE; base+=64){
    int j = base + lane; float val = 0.f; bool p = false;
    if (j < NNODE){
      val = (r < NNODE) ? Am[v*NNODE + j] : Am[j*NNODE + v];
      p = val > 0.f;
    }
    unsigned long long m = __ballot(p);
    int pre = __popcll(m & ((1ull << lane) - 1ull));
    if (p){ ip[cnt+pre]=j; vp[cnt+pre]=val; }
    cnt += __popcll(m);
    float vs = p ? val : 0.f;
    #pragma unroll
    for (int off=32; off; off>>=1) vs += __shfl_xor(vs, off);
    s += vs;
  }
  for (int e=lane; e<cnt; e+=64) vp[e] = vp[e] / s;
  if (lane==0) acnt[r]=cnt;
}

// ---------------- dilated inception (tanh * sigmoid), writes X bf16 ----------------
__global__ void __launch_bounds__(64) k_incep(const float* __restrict__ x,
    const float* __restrict__ fw2,const float* __restrict__ fb2,const float* __restrict__ gw2,const float* __restrict__ gb2,
    const float* __restrict__ fw3,const float* __restrict__ fb3,const float* __restrict__ gw3,const float* __restrict__ gb3,
    const float* __restrict__ fw6,const float* __restrict__ fb6,const float* __restrict__ gw6,const float* __restrict__ gb6,
    const float* __restrict__ fw7,const float* __restrict__ fb7,const float* __restrict__ gw7,const float* __restrict__ gb7,
    bf16* __restrict__ X){
  int b = blockIdx.x / NNODE, n = blockIdx.x % NNODE;
  int lane = threadIdx.x;
  __shared__ float xs[NC*NT];
  const float* xb = x + ((size_t)(b*NC)*NNODE + n)*NT;
  for (int c=0;c<NC;++c) xs[c*NT+lane] = xb[(size_t)c*NNODE*NT + lane];
  __syncthreads();
  int t = lane; bool act = t < NTOUT; int tc = act ? t : 0;
  float af[32], ag[32];
  #pragma unroll
  for (int o=0;o<8;++o){
    af[o]=fb2[o]; af[8+o]=fb3[o]; af[16+o]=fb6[o]; af[24+o]=fb7[o];
    ag[o]=gb2[o]; ag[8+o]=gb3[o]; ag[16+o]=gb6[o]; ag[24+o]=gb7[o];
  }
  for (int ic=0; ic<NC; ++ic){
    float xv[7];
    #pragma unroll
    for (int d=0;d<7;++d) xv[d] = xs[ic*NT + tc + d];
    #pragma unroll
    for (int o=0;o<8;++o){
      #pragma unroll
      for (int tp=0;tp<2;++tp){ af[o]    = fmaf(fw2[(o*NC+ic)*2+tp], xv[5+tp], af[o]);    ag[o]    = fmaf(gw2[(o*NC+ic)*2+tp], xv[5+tp], ag[o]); }
      #pragma unroll
      for (int tp=0;tp<3;++tp){ af[8+o]  = fmaf(fw3[(o*NC+ic)*3+tp], xv[4+tp], af[8+o]);  ag[8+o]  = fmaf(gw3[(o*NC+ic)*3+tp], xv[4+tp], ag[8+o]); }
      #pragma unroll
      for (int tp=0;tp<6;++tp){ af[16+o] = fmaf(fw6[(o*NC+ic)*6+tp], xv[1+tp], af[16+o]); ag[16+o] = fmaf(gw6[(o*NC+ic)*6+tp], xv[1+tp], ag[16+o]); }
      #pragma unroll
      for (int tp=0;tp<7;++tp){ af[24+o] = fmaf(fw7[(o*NC+ic)*7+tp], xv[tp],   af[24+o]); ag[24+o] = fmaf(gw7[(o*NC+ic)*7+tp], xv[tp],   ag[24+o]); }
    }
  }
  if (act){
    size_t ob = (size_t)b*BSLAB + (size_t)n*NTOUT + t;
    #pragma unroll
    for (int o=0;o<NC;++o){
      float fo = ftanh(af[o]);
      float go = fsig(ag[o]);
      X[ob + (size_t)o*SLAB] = f2b(fo*go);
    }
  }
}

// ---------------- skip path ----------------
__global__ void k_wT(const float* __restrict__ sw, float* __restrict__ wT){
  int id = blockIdx.x*blockDim.x + threadIdx.x;
  if (id >= 1856*64) return;
  int kk = id >> 6, sc = id & 63;
  wT[kk*64 + sc] = sw[sc*1856 + kk];
}

// 8 (b,n) pairs per block; 4 waves split K=1856; lane = skip channel.
__global__ void __launch_bounds__(256) k_skip(const bf16* __restrict__ X, const float* __restrict__ wT,
      const float* __restrict__ skip_b, const float* __restrict__ x_skip, float* __restrict__ out){
  __shared__ float Xs[8*1856];     // 59392 B; reused as reduction buffer afterwards
  int tid = threadIdx.x;
  int bp0 = blockIdx.x*8;
  for (int idx = tid; idx < 8*1856; idx += 256){
    int p = idx / 1856, kk = idx - p*1856;
    int c = kk / NTOUT, t = kk - c*NTOUT;
    int gp = bp0 + p; int b = gp / NNODE, n = gp - b*NNODE;
    Xs[idx] = b2f(X[(size_t)b*BSLAB + (size_t)c*SLAB + n*NTOUT + t]);
  }
  __syncthreads();
  int lane = tid & 63, w = tid >> 6;
  int kk0 = w*464;
  float acc[8] = {0,0,0,0,0,0,0,0};
  for (int kk = kk0; kk < kk0+464; kk += 4){
    float wv0 = wT[(kk+0)*64 + lane];
    float wv1 = wT[(kk+1)*64 + lane];
    float wv2 = wT[(kk+2)*64 + lane];
    float wv3 = wT[(kk+3)*64 + lane];
    #pragma unroll
    for (int p=0;p<8;++p){
      const float4 xv = *reinterpret_cast<const float4*>(&Xs[p*1856 + kk]);
      acc[p] = fmaf(xv.x, wv0, acc[p]);
      acc[p] = fmaf(xv.y, wv1, acc[p]);
      acc[p] = fmaf(xv.z, wv2, acc[p]);
      acc[p] = fmaf(xv.w, wv3, acc[p]);
    }
  }
  __syncthreads();                       // everyone done reading Xs
  float* red = Xs;                       // red[w][p][lane] = w*512 + p*64 + lane
  #pragma unroll
  for (int p=0;p<8;++p) red[w*512 + p*64 + lane] = acc[p];
  __syncthreads();
  #pragma unroll
  for (int pi=0; pi<2; ++pi){
    int p = w*2 + pi;
    float s = red[p*64+lane] + red[512+p*64+lane] + red[1024+p*64+lane] + red[1536+p*64+lane];
    int gp = bp0 + p, b = gp / NNODE, n = gp - b*NNODE;
    size_t so = (size_t)b*NSKIP*NNODE + (size_t)lane*NNODE + n;
    out[(size_t)XEL + so] = s + skip_b[lane] + x_skip[so];
  }
}

// ---------------- graph diffusion hop: Hout = 0.05*X + 0.95*(Ah (x) Hin) ----------------
// one block per (b, v); adjacency row staged in LDS; wave w owns channels w*8..w*8+7; lane = t
__global__ void __launch_bounds__(256) k_prop(const bf16* __restrict__ Hin, const bf16* __restrict__ Xb,
    bf16* __restrict__ Hout,
    const int* __restrict__ aidx, const float* __restrict__ aval, const int* __restrict__ acnt,
    int rowoff){
  __shared__ int   sidx[304];
  __shared__ float sval[304];
  int b = blockIdx.x / NNODE, v = blockIdx.x - b*NNODE;
  int r = rowoff + v;
  int cnt = acnt[r];
  for (int e = threadIdx.x; e < cnt; e += 256){
    sidx[e] = aidx[r*304 + e] * NTOUT;   // pre-scaled
    sval[e] = aval[r*304 + e];
  }
  __syncthreads();
  int lane = threadIdx.x & 63, w = threadIdx.x >> 6;
  int t = lane < NTOUT ? lane : NTOUT-1;
  const bf16* hb = Hin + (size_t)b*BSLAB + (size_t)(w*8)*SLAB + t;
  float acc[8] = {0,0,0,0,0,0,0,0};
  for (int j=0;j<cnt;++j){
    float vv = sval[j];
    int off = sidx[j];
    #pragma unroll
    for (int q=0;q<8;++q)
      acc[q] = fmaf(vv, b2f(hb[(size_t)q*SLAB + off]), acc[q]);
  }
  if (lane < NTOUT){
    size_t base = (size_t)b*BSLAB + (size_t)(w*8)*SLAB + (size_t)v*NTOUT + lane;
    #pragma unroll
    for (int q=0;q<8;++q){
      size_t o = base + (size_t)q*SLAB;
      Hout[o] = f2b(0.05f*b2f(Xb[o]) + 0.95f*acc[q]);
    }
  }
}

// ---------------- 1x1 conv accumulation passes ----------------
__global__ void k_wsum(const float* __restrict__ w1, const float* __restrict__ w2, float* __restrict__ wsum){
  int id = blockIdx.x*blockDim.x + threadIdx.x;
  if (id >= 1024) return;
  int c = id >> 5, c2 = id & 31;
  wsum[id] = w1[c*96 + c2] + w2[c*96 + c2];
}

__global__ void __launch_bounds__(256) k_mix1(const bf16* __restrict__ X, const bf16* __restrict__ HA,
    const bf16* __restrict__ HB, const float* __restrict__ wsum, const float* __restrict__ w1,
    const float* __restrict__ b1, const float* __restrict__ b2, float* __restrict__ out){
  int o = blockIdx.x*256 + threadIdx.x;            // 0 .. 556800
  int t = o % NTOUT; int v = (o / NTOUT) % NNODE; int b = o / SLAB;
  size_t base = (size_t)b*BSLAB + (size_t)v*NTOUT + t;
  float acc[32];
  #pragma unroll
  for (int c=0;c<32;++c) acc[c] = b1[c] + b2[c];
  for (int c2=0;c2<32;++c2){
    float xv = b2f(X[base + (size_t)c2*SLAB]);
    #pragma unroll
    for (int c=0;c<32;++c) acc[c] = fmaf(wsum[c*32+c2], xv, acc[c]);
  }
  for (int c2=0;c2<32;++c2){
    float hv = b2f(HA[base + (size_t)c2*SLAB]);
    #pragma unroll
    for (int c=0;c<32;++c) acc[c] = fmaf(w1[c*96+32+c2], hv, acc[c]);
  }
  for (int c2=0;c2<32;++c2){
    float hv = b2f(HB[base + (size_t)c2*SLAB]);
    #pragma unroll
    for (int c=0;c<32;++c) acc[c] = fmaf(w1[c*96+64+c2], hv, acc[c]);
  }
  #pragma unroll
  for (int c=0;c<32;++c) out[base + (size_t)c*SLAB] = acc[c];
}

__global__ void __launch_bounds__(256) k_mix2(const bf16* __restrict__ HA, const bf16* __restrict__ HB,
    const float* __restrict__ w2, const float* __restrict__ x, float* __restrict__ out){
  int o = blockIdx.x*256 + threadIdx.x;
  int t = o % NTOUT; int v = (o / NTOUT) % NNODE; int b = o / SLAB;
  size_t base = (size_t)b*BSLAB + (size_t)v*NTOUT + t;
  float acc[32];
  #pragma unroll
  for (int c=0;c<32;++c) acc[c] = out[base + (size_t)c*SLAB];
  for (int c2=0;c2<32;++c2){
    float hv = b2f(HA[base + (size_t)c2*SLAB]);
    #pragma unroll
    for (int c=0;c<32;++c) acc[c] = fmaf(w2[c*96+32+c2], hv, acc[c]);
  }
  for (int c2=0;c2<32;++c2){
    float hv = b2f(HB[base + (size_t)c2*SLAB]);
    #pragma unroll
    for (int c=0;c<32;++c) acc[c] = fmaf(w2[c*96+64+c2], hv, acc[c]);
  }
  #pragma unroll
  for (int c=0;c<32;++c){
    float res = x[((size_t)(b*NC+c)*NNODE + v)*NT + 6 + t];
    out[base + (size_t)c*SLAB] = acc[c] + res;
  }
}

// ---------------- layernorm ----------------
__global__ void __launch_bounds__(256) k_lnstat(const float* __restrict__ out, double* __restrict__ part){
  int blk = blockIdx.x; int b = blk >> 3, seg = blk & 7;
  const float* p = out + (size_t)b*BSLAB;
  int start = seg*69600, end = start + 69600;
  double s = 0.0, s2 = 0.0;
  for (int i = start + threadIdx.x; i < end; i += 256){
    double v = (double)p[i]; s += v; s2 += v*v;
  }
  #pragma unroll
  for (int off=32; off; off>>=1){ s += __shfl_down(s, off); s2 += __shfl_down(s2, off); }
  __shared__ double ls[4], ls2[4];
  int lane = threadIdx.x & 63, w = threadIdx.x >> 6;
  if (lane==0){ ls[w]=s; ls2[w]=s2; }
  __syncthreads();
  if (threadIdx.x==0){
    double a=0.0, a2=0.0;
    for (int i=0;i<4;++i){ a+=ls[i]; a2+=ls2[i]; }
    part[blk*2]=a; part[blk*2+1]=a2;
  }
}

__global__ void k_lnfin(const double* __restrict__ part, float* __restrict__ stats){
  int b = threadIdx.x; if (b >= 32) return;
  double s=0.0, s2=0.0;
  for (int seg=0; seg<8; ++seg){ s += part[(b*8+seg)*2]; s2 += part[(b*8+seg)*2+1]; }
  double n = (double)BSLAB;
  double mean = s/n;
  double var = s2/n - mean*mean;
  stats[b*2]   = (float)mean;
  stats[b*2+1] = (float)(1.0/sqrt(var + 1e-5));
}

__global__ void __launch_bounds__(256) k_lnapply(float* __restrict__ out, const float* __restrict__ stats,
        const float* __restrict__ lnw, const float* __restrict__ lnb, const int* __restrict__ idxp){
  int o = blockIdx.x*256 + threadIdx.x;
  int t = o % NTOUT; int v = (o / NTOUT) % NNODE; int c = (o / SLAB) % NC; int b = o / BSLAB;
  float mean = stats[b*2], rstd = stats[b*2+1];
  int vn = idxp[v];
  float wv = lnw[((size_t)c*NNODE + vn)*NTOUT + t];
  float bv = lnb[((size_t)c*NNODE + vn)*NTOUT + t];
  float vx = out[o];
  out[o] = (vx - mean)*rstd*wv + bv;
}

extern "C" void kernel_launch(void* const* d_in, const int* in_sizes, int n_in,
                              void* d_out, int out_size, void* d_ws, size_t ws_size,
                              hipStream_t stream) {
  (void)in_sizes; (void)n_in; (void)out_size; (void)ws_size;
  const float* x     = (const float*)d_in[0];
  const float* xskip = (const float*)d_in[1];
  const int*   idxp  = (const int*)d_in[2];
  const float* emb1  = (const float*)d_in[3];
  const float* emb2  = (const float*)d_in[4];
  const float* l1w   = (const float*)d_in[5];
  const float* l1b   = (const float*)d_in[6];
  const float* l2w   = (const float*)d_in[7];
  const float* l2b   = (const float*)d_in[8];
  const float* skw   = (const float*)d_in[9];
  const float* skb   = (const float*)d_in[10];
  const float* m1w   = (const float*)d_in[11];
  const float* m1b   = (const float*)d_in[12];
  const float* m2w   = (const float*)d_in[13];
  const float* m2b   = (const float*)d_in[14];
  const float* lnw   = (const float*)d_in[15];
  const float* lnb   = (const float*)d_in[16];
  const float* fw2=(const float*)d_in[17]; const float* fb2=(const float*)d_in[18];
  const float* gw2=(const float*)d_in[19]; const float* gb2=(const float*)d_in[20];
  const float* fw3=(const float*)d_in[21]; const float* fb3=(const float*)d_in[22];
  const float* gw3=(const float*)d_in[23]; const float* gb3=(const float*)d_in[24];
  const float* fw6=(const float*)d_in[25]; const float* fb6=(const float*)d_in[26];
  const float* gw6=(const float*)d_in[27]; const float* gb6=(const float*)d_in[28];
  const float* fw7=(const float*)d_in[29]; const float* fb7=(const float*)d_in[30];
  const float* gw7=(const float*)d_in[31]; const float* gb7=(const float*)d_in[32];
  float* out = (float*)d_out;

  char* wsbase = (char*)d_ws;
  size_t cur = 0;
  auto alloc = [&](size_t bytes)->char*{
    char* p = wsbase + cur;
    cur = (cur + bytes + 255) & ~(size_t)255;
    return p;
  };
  bf16*  X    = (bf16*) alloc((size_t)XEL*2);
  bf16*  HA   = (bf16*) alloc((size_t)XEL*2);
  bf16*  HB   = (bf16*) alloc((size_t)XEL*2);
  float* n1   = (float*)alloc(12000*4);
  float* n2   = (float*)alloc(12000*4);
  float* Am   = (float*)alloc(90000*4);
  int*   aidx = (int*)  alloc(600*304*4);
  float* aval = (float*)alloc(600*304*4);
  int*   acnt = (int*)  alloc(600*4);
  float* wT   = (float*)alloc(1856*64*4);
  float* wsum = (float*)alloc(1024*4);
  double* part = (double*)alloc(256*2*8);
  float* stats = (float*)alloc(64*4);

  // graph construction (tiny)
  k_nodes <<<NNODE, 64, 0, stream>>>(emb1, emb2, l1w, l1b, l2w, l2b, idxp, n1, n2);
  k_adjrow<<<NNODE, 64, 0, stream>>>(n1, n2, Am);
  k_csr   <<<2*NNODE, 64, 0, stream>>>(Am, aidx, aval, acnt);

  // dilated inception -> X (bf16)
  k_incep<<<NB*NNODE, 64, 0, stream>>>(x,
      fw2,fb2,gw2,gb2, fw3,fb3,gw3,gb3, fw6,fb6,gw6,gb6, fw7,fb7,gw7,gb7, X);

  // skip path
  k_wT  <<<(1856*64)/256, 256, 0, stream>>>(skw, wT);
  k_wsum<<<4, 256, 0, stream>>>(m1w, m2w, wsum);
  k_skip<<<(NB*NNODE)/8, 256, 0, stream>>>(X, wT, skb, xskip, out);

  // mixprop over Ah1
  k_prop<<<NB*NNODE, 256, 0, stream>>>(X,  X, HA, aidx, aval, acnt, 0);
  k_prop<<<NB*NNODE, 256, 0, stream>>>(HA, X, HB, aidx, aval, acnt, 0);
  k_mix1<<<BSLAB/256, 256, 0, stream>>>(X, HA, HB, wsum, m1w, m1b, m2b, out);

  // mixprop over Ah2 (= A^T), reuse hop buffers
  k_prop<<<NB*NNODE, 256, 0, stream>>>(X,  X, HA, aidx, aval, acnt, NNODE);
  k_prop<<<NB*NNODE, 256, 0, stream>>>(HA, X, HB, aidx, aval, acnt, NNODE);
  k_mix2<<<BSLAB/256, 256, 0, stream>>>(HA, HB, m2w, x, out);

  // layernorm
  k_lnstat<<<256, 256, 0, stream>>>(out, part);
  k_lnfin<<<1, 32, 0, stream>>>(part, stats);
  k_lnapply<<<XEL/256, 256, 0, stream>>>(out, stats, lnw, lnb, idxp);
}